// Round 9
// baseline (408.400 us; speedup 1.0000x reference)
//
#include <hip/hip_runtime.h>
#include <cstdint>
#include <cstddef>

#define B_ 2
#define S_ 2048
#define HID_ 1024
#define NH_ 8
#define NKV_ 2
#define HD_ 256
#define ROT_ 128
#define TOK_ (B_ * S_)
#define SCALE_ 0.0625f

typedef __attribute__((ext_vector_type(8))) short s16x8;
typedef __attribute__((ext_vector_type(4))) float f32x4;

__device__ __forceinline__ float bf2f(short u) {
  unsigned t = ((unsigned)(unsigned short)u) << 16;
  float f;
  __builtin_memcpy(&f, &t, 4);
  return f;
}
__device__ __forceinline__ short f2bf(float f) {
  unsigned u;
  __builtin_memcpy(&u, &f, 4);
  u += 0x7fffu + ((u >> 16) & 1);
  return (short)(u >> 16);
}

// async global->LDS 16B (gfx950). LDS dest is wave-uniform base + lane*16.
__device__ __forceinline__ void gl16(const void* g, void* l) {
  __builtin_amdgcn_global_load_lds((const __attribute__((address_space(1))) int*)g,
                                   (__attribute__((address_space(3))) int*)l, 16, 0, 0);
}

// ---------------- elementwise cast fp32 -> bf16 ----------------
__global__ __launch_bounds__(256) void k_cast(const float* __restrict__ in,
                                              short* __restrict__ out, int n) {
  int i = blockIdx.x * 256 + threadIdx.x;
  if (i < n) out[i] = f2bf(in[i]);
}

// ---------------- tiled transpose + cast: in[R][C] fp32 -> out[C][R] bf16 ----------------
__global__ __launch_bounds__(256) void k_wtrans(const float* __restrict__ in,
                                                short* __restrict__ out, int R, int C) {
  __shared__ short tile[32][33];
  int tx = threadIdx.x & 31, ty = threadIdx.x >> 5;
  int r0 = blockIdx.y * 32, c0 = blockIdx.x * 32;
#pragma unroll
  for (int p = 0; p < 4; ++p)
    tile[ty + p * 8][tx] = f2bf(in[(size_t)(r0 + ty + p * 8) * C + c0 + tx]);
  __syncthreads();
#pragma unroll
  for (int p = 0; p < 4; ++p)
    out[(size_t)(c0 + ty + p * 8) * R + r0 + tx] = tile[tx][ty + p * 8];
}

// ---------------- V transpose: kvp v-part -> Vtg[b*2+kvh][256][2048] bf16 ----------------
__global__ __launch_bounds__(256) void k_vtrans(const short* __restrict__ kvp,
                                                short* __restrict__ Vtg) {
  __shared__ short tile[32][33];
  int bh = blockIdx.z;
  int b = bh >> 1, kvh = bh & 1;
  int s0 = blockIdx.x * 32, d0 = blockIdx.y * 32;
  int tx = threadIdx.x & 31, ty = threadIdx.x >> 5;
#pragma unroll
  for (int p = 0; p < 4; ++p) {
    int sr = ty + p * 8;
    tile[sr][tx] = kvp[(size_t)(b * S_ + s0 + sr) * 1024 + 512 + kvh * 256 + d0 + tx];
  }
  __syncthreads();
#pragma unroll
  for (int p = 0; p < 4; ++p) {
    int dr = ty + p * 8;
    Vtg[((size_t)bh * 256 + d0 + dr) * 2048 + s0 + tx] = tile[tx][dr];
  }
}

// ---------------- GEMM 128x128 (for skinny N): BK=64, gl16 staging, XOR swizzle ------
template <int OUT_BF16>
__global__ __launch_bounds__(256) void k_gemm_bt(const short* __restrict__ A,
                                                 const short* __restrict__ Bt,
                                                 void* __restrict__ Cv, int M, int N, int K) {
  __shared__ short As[128 * 64];
  __shared__ short Bs[128 * 64];
  const int tid = threadIdx.x;
  const int bm = blockIdx.y * 128, bn = blockIdx.x * 128;
  const int w = tid >> 6, lane = tid & 63, lo = lane & 15, hi = lane >> 4;
  const int wr = (w >> 1) * 64, wc = (w & 1) * 64;
  f32x4 acc[4][4] = {};
  for (int k0 = 0; k0 < K; k0 += 64) {
#pragma unroll
    for (int rnd = 0; rnd < 4; ++rnd) {
      int i = rnd * 256 + tid;
      int row = i >> 3, c = i & 7;
      int src_col = (c ^ (row & 7)) * 8;
      gl16(&A[(size_t)(bm + row) * K + k0 + src_col], (char*)As + (size_t)i * 16);
      gl16(&Bt[(size_t)(bn + row) * K + k0 + src_col], (char*)Bs + (size_t)i * 16);
    }
    __syncthreads();
    s16x8 af[2][4], bfr[2][4];
#pragma unroll
    for (int kk = 0; kk < 2; ++kk) {
#pragma unroll
      for (int m = 0; m < 4; ++m) {
        int row = wr + m * 16 + lo;
        af[kk][m] = *(const s16x8*)&As[row * 64 + (((kk * 4 + hi) ^ (row & 7)) * 8)];
      }
#pragma unroll
      for (int n = 0; n < 4; ++n) {
        int row = wc + n * 16 + lo;
        bfr[kk][n] = *(const s16x8*)&Bs[row * 64 + (((kk * 4 + hi) ^ (row & 7)) * 8)];
      }
    }
#pragma unroll
    for (int kk = 0; kk < 2; ++kk)
#pragma unroll
      for (int m = 0; m < 4; ++m)
#pragma unroll
        for (int n = 0; n < 4; ++n)
          acc[m][n] =
              __builtin_amdgcn_mfma_f32_16x16x32_bf16(af[kk][m], bfr[kk][n], acc[m][n], 0, 0, 0);
    __syncthreads();
  }
#pragma unroll
  for (int m = 0; m < 4; ++m)
#pragma unroll
    for (int n = 0; n < 4; ++n)
#pragma unroll
      for (int r = 0; r < 4; ++r) {
        int row = bm + wr + m * 16 + hi * 4 + r;
        int col = bn + wc + n * 16 + lo;
        if (OUT_BF16)
          ((short*)Cv)[(size_t)row * N + col] = f2bf(acc[m][n][r]);
        else
          ((float*)Cv)[(size_t)row * N + col] = acc[m][n][r];
      }
}

// ---------------- GEMM 256x256, 8 waves, BK=64 (2-phase structure) ----------------
template <int OUT_BF16>
__global__ __launch_bounds__(512) void k_gemm256(const short* __restrict__ A,
                                                 const short* __restrict__ Bt,
                                                 void* __restrict__ Cv, int M, int N, int K) {
  __shared__ short As[256 * 64];
  __shared__ short Bs[256 * 64];
  const int tid = threadIdx.x;
  const int bm = blockIdx.y * 256, bn = blockIdx.x * 256;
  const int w = tid >> 6, lane = tid & 63, lo = lane & 15, hi = lane >> 4;
  const int wr = (w >> 2) * 128, wc = (w & 3) * 64;
  f32x4 acc[8][4] = {};
  for (int k0 = 0; k0 < K; k0 += 64) {
#pragma unroll
    for (int rnd = 0; rnd < 4; ++rnd) {
      int i = rnd * 512 + tid;
      int row = i >> 3, c = i & 7;
      int src_col = (c ^ (row & 7)) * 8;
      gl16(&A[(size_t)(bm + row) * K + k0 + src_col], (char*)As + (size_t)i * 16);
      gl16(&Bt[(size_t)(bn + row) * K + k0 + src_col], (char*)Bs + (size_t)i * 16);
    }
    __syncthreads();
#pragma unroll
    for (int kk = 0; kk < 2; ++kk) {
      s16x8 af[8], bfr[4];
#pragma unroll
      for (int m = 0; m < 8; ++m) {
        int row = wr + m * 16 + lo;
        af[m] = *(const s16x8*)&As[row * 64 + (((kk * 4 + hi) ^ (row & 7)) * 8)];
      }
#pragma unroll
      for (int n = 0; n < 4; ++n) {
        int row = wc + n * 16 + lo;
        bfr[n] = *(const s16x8*)&Bs[row * 64 + (((kk * 4 + hi) ^ (row & 7)) * 8)];
      }
#pragma unroll
      for (int m = 0; m < 8; ++m)
#pragma unroll
        for (int n = 0; n < 4; ++n)
          acc[m][n] = __builtin_amdgcn_mfma_f32_16x16x32_bf16(af[m], bfr[n], acc[m][n], 0, 0, 0);
    }
    __syncthreads();
  }
#pragma unroll
  for (int m = 0; m < 8; ++m)
#pragma unroll
    for (int n = 0; n < 4; ++n)
#pragma unroll
      for (int r = 0; r < 4; ++r) {
        int row = bm + wr + m * 16 + hi * 4 + r;
        int col = bn + wc + n * 16 + lo;
        if (OUT_BF16)
          ((short*)Cv)[(size_t)row * N + col] = f2bf(acc[m][n][r]);
        else
          ((float*)Cv)[(size_t)row * N + col] = acc[m][n][r];
      }
}

// ---------------- per-(token,head) RMSNorm + RoPE, bf16 in/out ----------------
template <int NHEAD, int IN_ROW, int IN_HS>
__global__ __launch_bounds__(256) void k_norm_rope(const short* __restrict__ xin,
                                                   const float* __restrict__ wn,
                                                   const float* __restrict__ cosb,
                                                   const float* __restrict__ sinb,
                                                   short* __restrict__ xout) {
  int blk = blockIdx.x;
  int h = blk % NHEAD;
  int ts = blk / NHEAD;
  int d = threadIdx.x;
  float x = bf2f(xin[(size_t)ts * IN_ROW + h * IN_HS + d]);
  float ss = x * x;
#pragma unroll
  for (int m = 32; m >= 1; m >>= 1) ss += __shfl_xor(ss, m);
  __shared__ float sred[4];
  __shared__ float sn[256];
  int wid = d >> 6;
  if ((d & 63) == 0) sred[wid] = ss;
  __syncthreads();
  float tot = sred[0] + sred[1] + sred[2] + sred[3];
  float nv = x * rsqrtf(tot * (1.0f / 256.0f) + 1e-6f) * (1.0f + wn[d]);
  sn[d] = nv;
  __syncthreads();
  float o;
  if (d < 128) {
    float c = cosb[(size_t)ts * 128 + d];
    float s = sinb[(size_t)ts * 128 + d];
    o = (d < 64) ? (nv * c - sn[d + 64] * s) : (nv * c + sn[d - 64] * s);
  } else {
    o = nv;
  }
  xout[(size_t)blk * 256 + d] = f2bf(o);
}

// ---------------- GQA causal flash attention + sigmoid gate ----------------
// 256 blocks, 8 waves (512 thr, 2/SIMD), QBLK=128. Wave = (kv-half, q-group):
// qg = w&3 owns 32 q-rows (2 row-frags), kh = w>>2 owns 32 of each 64-kv tile.
// Each wave reads ONLY its kv-half of K/V from LDS (32 reads/iter vs 64) -> per-CU
// LDS traffic halved vs R7 while keeping 2 waves/SIMD TLP. Independent online
// softmax per kv-half; one-time LDS merge at the end (factor exp(m_i - m) kills
// any all-masked half's junk partial). Swapped QK^T keeps softmax in-register.
#define ATTN_LDS 135168
__global__ __launch_bounds__(512, 2) void k_attn(const short* __restrict__ qb,
                                                 const short* __restrict__ kb,
                                                 const short* __restrict__ Vtg,
                                                 const short* __restrict__ qg,
                                                 short* __restrict__ og) {
  extern __shared__ char smem[];
  short* KbufS = (short*)smem;            // 2 bufs x [64 rows][32 chunks x 8]
  short* VbufS = (short*)(smem + 65536);  // 2 bufs x [256 rows][8 chunks x 8]
  float* Obuf = (float*)smem;             // post-loop: [128][260] f32 = 133120 B
  float* mlbuf = (float*)(smem + 133120); // post-loop: m[2][4][2][16] + l[...] = 2048 B

  // XCD-aware decode: xcd = blockIdx % 8; (b,kvh) stream pinned to an XCD pair.
  const int raw = blockIdx.x;
  const int xcd = raw & 7, slot = raw >> 3;
  const int p = xcd >> 1, side = xcd & 1;
  const int id = side * 32 + slot;
  const int hgi = id & 3, qt = id >> 2;
  const int b = p >> 1, kvh = p & 1, h = kvh * 4 + hgi;
  const int q0 = qt * 128;
  const int tid = threadIdx.x;
  const int w = tid >> 6, lane = tid & 63, lo = lane & 15, hi = lane >> 4;
  const int qg_ = w & 3, kh = w >> 2;
  const int swz = lo & 7;

  const short* kbase = kb + ((size_t)(b * S_) * NKV_ + kvh) * HD_;
  const short* vbase = Vtg + (size_t)(b * 2 + kvh) * 256 * 2048;

  auto stage = [&](int kv0, int nb) {
#pragma unroll
    for (int rnd = 0; rnd < 4; ++rnd) {
      int i = rnd * 512 + tid;
      {
        int row = i >> 5, c = i & 31;
        const short* src = kbase + (size_t)(kv0 + row) * 512 + ((c ^ (row & 7)) * 8);
        gl16(src, smem + (size_t)nb * 32768 + (size_t)i * 16);
      }
      {
        int row = i >> 3, c = i & 7;
        const short* src = vbase + (size_t)row * 2048 + kv0 + ((c ^ (row & 7)) * 8);
        gl16(src, smem + 65536 + (size_t)nb * 32768 + (size_t)i * 16);
      }
    }
  };

  // Q fragments, two row-frags per wave: s -> rows q0 + qg_*32 + s*16 + lo
  s16x8 qf[2][8];
#pragma unroll
  for (int s = 0; s < 2; ++s) {
    size_t base = ((size_t)((b * S_ + q0 + qg_ * 32 + s * 16 + lo) * NH_) + h) * HD_;
#pragma unroll
    for (int t = 0; t < 8; ++t) qf[s][t] = *(const s16x8*)&qb[base + t * 32 + hi * 8];
  }
  f32x4 acc[2][16];
#pragma unroll
  for (int s = 0; s < 2; ++s)
#pragma unroll
    for (int t = 0; t < 16; ++t) acc[s][t] = (f32x4){0.f, 0.f, 0.f, 0.f};
  float m_run[2] = {-1e30f, -1e30f}, l_run[2] = {0.f, 0.f};
  const int qrow[2] = {q0 + qg_ * 32 + lo, q0 + qg_ * 32 + 16 + lo};

  stage(0, 0);
  __syncthreads();

  const int ntiles = 2 * qt + 2;
  int n = 0;
#pragma unroll 1
  for (int it = 0; it < ntiles; ++it) {
    const int kv0 = it * 64;
    if (it + 1 < ntiles) stage(kv0 + 64, n ^ 1);

    const short* Kb = KbufS + n * 16384;
    const short* Vb = VbufS + n * 16384;

    // S^T = K @ Q^T over this wave's 32-kv half (2 local nt)
    f32x4 sac[2][2];
#pragma unroll
    for (int s = 0; s < 2; ++s)
#pragma unroll
      for (int nt = 0; nt < 2; ++nt) sac[s][nt] = (f32x4){0.f, 0.f, 0.f, 0.f};
#pragma unroll
    for (int nt = 0; nt < 2; ++nt) {
      s16x8 kf[8];
#pragma unroll
      for (int t = 0; t < 8; ++t)
        kf[t] = *(const s16x8*)&Kb[(kh * 32 + nt * 16 + lo) * 256 + (((t * 4 + hi) ^ swz) * 8)];
#pragma unroll
      for (int t = 0; t < 8; ++t) {
        sac[0][nt] = __builtin_amdgcn_mfma_f32_16x16x32_bf16(kf[t], qf[0][t], sac[0][nt], 0, 0, 0);
        sac[1][nt] = __builtin_amdgcn_mfma_f32_16x16x32_bf16(kf[t], qf[1][t], sac[1][nt], 0, 0, 0);
      }
    }

    // in-register softmax per row-frag over 8 lane-local P values; pack to bf16
    int pk0[2][2], pk1[2][2];
#pragma unroll
    for (int s = 0; s < 2; ++s) {
      float pl[2][4];
      float mx = -1e30f;
#pragma unroll
      for (int nt = 0; nt < 2; ++nt)
#pragma unroll
        for (int r = 0; r < 4; ++r) {
          int kv = kv0 + kh * 32 + nt * 16 + hi * 4 + r;
          float v = sac[s][nt][r] * SCALE_;
          if (kv > qrow[s]) v = -1e30f;
          pl[nt][r] = v;
          mx = fmaxf(mx, v);
        }
      mx = fmaxf(mx, __shfl_xor(mx, 16));
      mx = fmaxf(mx, __shfl_xor(mx, 32));
      if (!__all(mx <= m_run[s] + 8.f)) {  // T13 defer-rescale
        float mnew = fmaxf(m_run[s], mx);
        float fs = __expf(m_run[s] - mnew);
        m_run[s] = mnew;
        l_run[s] *= fs;
        float f0 = __shfl(fs, 4 * hi + 0);
        float f1 = __shfl(fs, 4 * hi + 1);
        float f2 = __shfl(fs, 4 * hi + 2);
        float f3 = __shfl(fs, 4 * hi + 3);
#pragma unroll
        for (int t = 0; t < 16; ++t) {
          acc[s][t][0] *= f0;
          acc[s][t][1] *= f1;
          acc[s][t][2] *= f2;
          acc[s][t][3] *= f3;
        }
      }
      float rs = 0.f;
#pragma unroll
      for (int nt = 0; nt < 2; ++nt)
#pragma unroll
        for (int r = 0; r < 4; ++r) {
          pl[nt][r] = __expf(pl[nt][r] - m_run[s]);
          rs += pl[nt][r];
        }
      rs += __shfl_xor(rs, 16);
      rs += __shfl_xor(rs, 32);
      l_run[s] += rs;
#pragma unroll
      for (int nt = 0; nt < 2; ++nt) {
        asm("v_cvt_pk_bf16_f32 %0, %1, %2" : "=v"(pk0[s][nt]) : "v"(pl[nt][0]), "v"(pl[nt][1]));
        asm("v_cvt_pk_bf16_f32 %0, %1, %2" : "=v"(pk1[s][nt]) : "v"(pl[nt][2]), "v"(pl[nt][3]));
      }
    }

    // PV over this wave's 32-kv half: pa gathered per row-frag; vf shared (1:2)
    s16x8 pa[2];
#pragma unroll
    for (int s = 0; s < 2; ++s) {
      int pw[4];
#pragma unroll
      for (int dw = 0; dw < 4; ++dw) {
        int srcl = (2 * (hi & 1) + (dw >> 1)) * 16 + lo;
        int vA = __shfl((dw & 1) ? pk1[s][0] : pk0[s][0], srcl);
        int vB = __shfl((dw & 1) ? pk1[s][1] : pk0[s][1], srcl);
        pw[dw] = (hi & 2) ? vB : vA;
      }
      __builtin_memcpy(&pa[s], pw, 16);
    }
#pragma unroll
    for (int g = 0; g < 2; ++g) {
      s16x8 vf[8];
#pragma unroll
      for (int u = 0; u < 8; ++u) {
        int t = g * 8 + u;
        vf[u] = *(const s16x8*)&Vb[(t * 16 + lo) * 64 + (((kh * 4 + hi) ^ swz) * 8)];
      }
#pragma unroll
      for (int u = 0; u < 8; ++u) {
        int t = g * 8 + u;
        acc[0][t] = __builtin_amdgcn_mfma_f32_16x16x32_bf16(pa[0], vf[u], acc[0][t], 0, 0, 0);
        acc[1][t] = __builtin_amdgcn_mfma_f32_16x16x32_bf16(pa[1], vf[u], acc[1][t], 0, 0, 0);
      }
    }
    __syncthreads();
    n ^= 1;
  }

  // ---- merge the two kv-halves (per q-group) via LDS ----
  if (hi == 0) {
#pragma unroll
    for (int s = 0; s < 2; ++s) {
      mlbuf[((kh * 4 + qg_) * 2 + s) * 16 + lo] = m_run[s];
      mlbuf[256 + ((kh * 4 + qg_) * 2 + s) * 16 + lo] = l_run[s];
    }
  }
  __syncthreads();
  float fsr[2][4], lt[2];
#pragma unroll
  for (int s = 0; s < 2; ++s) {
    float mo = mlbuf[(((1 - kh) * 4 + qg_) * 2 + s) * 16 + lo];
    float lo_ = mlbuf[256 + (((1 - kh) * 4 + qg_) * 2 + s) * 16 + lo];
    float mm = fmaxf(m_run[s], mo);
    float fs_ = __expf(m_run[s] - mm);
    float fo_ = __expf(mo - mm);
    lt[s] = l_run[s] * fs_ + lo_ * fo_;
#pragma unroll
    for (int r = 0; r < 4; ++r) fsr[s][r] = __shfl(fs_, 4 * hi + r);
  }
  __syncthreads();  // mlbuf reads done before Obuf (alias region) writes
  if (kh == 1) {
#pragma unroll
    for (int s = 0; s < 2; ++s)
#pragma unroll
      for (int t = 0; t < 16; ++t)
#pragma unroll
        for (int r = 0; r < 4; ++r)
          Obuf[(qg_ * 32 + s * 16 + hi * 4 + r) * 260 + t * 16 + lo] = acc[s][t][r] * fsr[s][r];
  }
  __syncthreads();
  if (kh == 0) {
#pragma unroll
    for (int s = 0; s < 2; ++s) {
      float linv[4];
#pragma unroll
      for (int r = 0; r < 4; ++r) linv[r] = 1.0f / __shfl(lt[s], 4 * hi + r);
#pragma unroll
      for (int t = 0; t < 16; ++t)
#pragma unroll
        for (int r = 0; r < 4; ++r) {
          int row = q0 + qg_ * 32 + s * 16 + hi * 4 + r;
          int hd = t * 16 + lo;
          float o = (acc[s][t][r] * fsr[s][r] +
                     Obuf[(qg_ * 32 + s * 16 + hi * 4 + r) * 260 + t * 16 + lo]) *
                    linv[r];
          float g = bf2f(qg[(size_t)(b * S_ + row) * 4096 + h * 512 + 256 + hd]);
          float sg = 1.0f / (1.0f + __expf(-g));
          og[(size_t)(b * S_ + row) * 2048 + h * 256 + hd] = f2bf(o * sg);
        }
    }
  }
}

extern "C" void kernel_launch(void* const* d_in, const int* in_sizes, int n_in, void* d_out,
                              int out_size, void* d_ws, size_t ws_size, hipStream_t stream) {
  const float* hidden = (const float*)d_in[0];
  const float* cosb = (const float*)d_in[1];
  const float* sinb = (const float*)d_in[2];
  const float* Wq = (const float*)d_in[3];
  const float* Wk = (const float*)d_in[4];
  const float* Wv = (const float*)d_in[5];
  const float* Wo = (const float*)d_in[6];
  const float* qw = (const float*)d_in[7];
  const float* kw = (const float*)d_in[8];
  float* out = (float*)d_out;

  char* ws = (char*)d_ws;
  size_t off = 0;
  auto alloc = [&](size_t bytes) {
    void* p = ws + off;
    off += (bytes + 255) & ~(size_t)255;
    return p;
  };
  short* hb = (short*)alloc((size_t)TOK_ * HID_ * 2);
  short* WqT = (short*)alloc((size_t)4096 * 1024 * 2);
  short* kvT = (short*)alloc((size_t)1024 * 1024 * 2);
  short* WoT = (short*)alloc((size_t)1024 * 2048 * 2);
  short* qg = (short*)alloc((size_t)TOK_ * 4096 * 2);
  short* kvp = (short*)alloc((size_t)TOK_ * 1024 * 2);
  short* qb = (short*)alloc((size_t)TOK_ * 2048 * 2);
  short* kb = (short*)alloc((size_t)TOK_ * 512 * 2);
  short* og = (short*)alloc((size_t)TOK_ * 2048 * 2);
  short* Vtg = WqT;  // reuse: WqT dead after GEMM1
  (void)ws_size;
  (void)in_sizes;
  (void)n_in;
  (void)out_size;

  hipFuncSetAttribute((const void*)k_attn, hipFuncAttributeMaxDynamicSharedMemorySize,
                      ATTN_LDS);

  k_cast<<<(TOK_ * HID_ + 255) / 256, 256, 0, stream>>>(hidden, hb, TOK_ * HID_);
  k_wtrans<<<dim3(4096 / 32, 1024 / 32), 256, 0, stream>>>(Wq, WqT, 1024, 4096);
  k_wtrans<<<dim3(512 / 32, 1024 / 32), 256, 0, stream>>>(Wk, kvT, 1024, 512);
  k_wtrans<<<dim3(512 / 32, 1024 / 32), 256, 0, stream>>>(Wv, kvT + 512 * 1024, 1024, 512);
  k_wtrans<<<dim3(1024 / 32, 2048 / 32), 256, 0, stream>>>(Wo, WoT, 2048, 1024);

  k_gemm256<1><<<dim3(16, 16), 512, 0, stream>>>(hb, WqT, qg, 4096, 4096, 1024);
  k_gemm_bt<1><<<dim3(8, 32), 256, 0, stream>>>(hb, kvT, kvp, 4096, 1024, 1024);

  k_norm_rope<NH_, 4096, 512><<<TOK_ * NH_, 256, 0, stream>>>(qg, qw, cosb, sinb, qb);
  k_norm_rope<NKV_, 1024, 256><<<TOK_ * NKV_, 256, 0, stream>>>(kvp, kw, cosb, sinb, kb);
  k_vtrans<<<dim3(64, 8, 4), 256, 0, stream>>>(kvp, Vtg);

  k_attn<<<256, 512, ATTN_LDS, stream>>>(qb, kb, Vtg, qg, og);

  k_gemm_bt<0><<<dim3(8, 32), 256, 0, stream>>>(og, WoT, out, 4096, 1024, 2048);
}

// Round 10
// 407.709 us; speedup vs baseline: 1.0017x; 1.0017x over previous
//
#include <hip/hip_runtime.h>
#include <cstdint>
#include <cstddef>

#define B_ 2
#define S_ 2048
#define HID_ 1024
#define NH_ 8
#define NKV_ 2
#define HD_ 256
#define ROT_ 128
#define TOK_ (B_ * S_)
#define SCALE_ 0.0625f

typedef __attribute__((ext_vector_type(8))) short s16x8;
typedef __attribute__((ext_vector_type(4))) float f32x4;

__device__ __forceinline__ float bf2f(short u) {
  unsigned t = ((unsigned)(unsigned short)u) << 16;
  float f;
  __builtin_memcpy(&f, &t, 4);
  return f;
}
__device__ __forceinline__ short f2bf(float f) {
  unsigned u;
  __builtin_memcpy(&u, &f, 4);
  u += 0x7fffu + ((u >> 16) & 1);
  return (short)(u >> 16);
}

// async global->LDS 16B (gfx950). LDS dest is wave-uniform base + lane*16.
__device__ __forceinline__ void gl16(const void* g, void* l) {
  __builtin_amdgcn_global_load_lds((const __attribute__((address_space(1))) int*)g,
                                   (__attribute__((address_space(3))) int*)l, 16, 0, 0);
}

// ---------------- elementwise cast fp32 -> bf16 ----------------
__global__ __launch_bounds__(256) void k_cast(const float* __restrict__ in,
                                              short* __restrict__ out, int n) {
  int i = blockIdx.x * 256 + threadIdx.x;
  if (i < n) out[i] = f2bf(in[i]);
}

// ---------------- tiled transpose + cast: in[R][C] fp32 -> out[C][R] bf16 ----------------
__global__ __launch_bounds__(256) void k_wtrans(const float* __restrict__ in,
                                                short* __restrict__ out, int R, int C) {
  __shared__ short tile[32][33];
  int tx = threadIdx.x & 31, ty = threadIdx.x >> 5;
  int r0 = blockIdx.y * 32, c0 = blockIdx.x * 32;
#pragma unroll
  for (int p = 0; p < 4; ++p)
    tile[ty + p * 8][tx] = f2bf(in[(size_t)(r0 + ty + p * 8) * C + c0 + tx]);
  __syncthreads();
#pragma unroll
  for (int p = 0; p < 4; ++p)
    out[(size_t)(c0 + ty + p * 8) * R + r0 + tx] = tile[tx][ty + p * 8];
}

// ---------------- V transpose: kvp v-part -> Vtg[b*2+kvh][256][2048] bf16 ----------------
__global__ __launch_bounds__(256) void k_vtrans(const short* __restrict__ kvp,
                                                short* __restrict__ Vtg) {
  __shared__ short tile[32][33];
  int bh = blockIdx.z;
  int b = bh >> 1, kvh = bh & 1;
  int s0 = blockIdx.x * 32, d0 = blockIdx.y * 32;
  int tx = threadIdx.x & 31, ty = threadIdx.x >> 5;
#pragma unroll
  for (int p = 0; p < 4; ++p) {
    int sr = ty + p * 8;
    tile[sr][tx] = kvp[(size_t)(b * S_ + s0 + sr) * 1024 + 512 + kvh * 256 + d0 + tx];
  }
  __syncthreads();
#pragma unroll
  for (int p = 0; p < 4; ++p) {
    int dr = ty + p * 8;
    Vtg[((size_t)bh * 256 + d0 + dr) * 2048 + s0 + tx] = tile[tx][dr];
  }
}

// ---------------- GEMM 128x128 (for skinny N): BK=64, gl16 staging, XOR swizzle ------
template <int OUT_BF16>
__global__ __launch_bounds__(256) void k_gemm_bt(const short* __restrict__ A,
                                                 const short* __restrict__ Bt,
                                                 void* __restrict__ Cv, int M, int N, int K) {
  __shared__ short As[128 * 64];
  __shared__ short Bs[128 * 64];
  const int tid = threadIdx.x;
  const int bm = blockIdx.y * 128, bn = blockIdx.x * 128;
  const int w = tid >> 6, lane = tid & 63, lo = lane & 15, hi = lane >> 4;
  const int wr = (w >> 1) * 64, wc = (w & 1) * 64;
  f32x4 acc[4][4] = {};
  for (int k0 = 0; k0 < K; k0 += 64) {
#pragma unroll
    for (int rnd = 0; rnd < 4; ++rnd) {
      int i = rnd * 256 + tid;
      int row = i >> 3, c = i & 7;
      int src_col = (c ^ (row & 7)) * 8;
      gl16(&A[(size_t)(bm + row) * K + k0 + src_col], (char*)As + (size_t)i * 16);
      gl16(&Bt[(size_t)(bn + row) * K + k0 + src_col], (char*)Bs + (size_t)i * 16);
    }
    __syncthreads();
    s16x8 af[2][4], bfr[2][4];
#pragma unroll
    for (int kk = 0; kk < 2; ++kk) {
#pragma unroll
      for (int m = 0; m < 4; ++m) {
        int row = wr + m * 16 + lo;
        af[kk][m] = *(const s16x8*)&As[row * 64 + (((kk * 4 + hi) ^ (row & 7)) * 8)];
      }
#pragma unroll
      for (int n = 0; n < 4; ++n) {
        int row = wc + n * 16 + lo;
        bfr[kk][n] = *(const s16x8*)&Bs[row * 64 + (((kk * 4 + hi) ^ (row & 7)) * 8)];
      }
    }
#pragma unroll
    for (int kk = 0; kk < 2; ++kk)
#pragma unroll
      for (int m = 0; m < 4; ++m)
#pragma unroll
        for (int n = 0; n < 4; ++n)
          acc[m][n] =
              __builtin_amdgcn_mfma_f32_16x16x32_bf16(af[kk][m], bfr[kk][n], acc[m][n], 0, 0, 0);
    __syncthreads();
  }
#pragma unroll
  for (int m = 0; m < 4; ++m)
#pragma unroll
    for (int n = 0; n < 4; ++n)
#pragma unroll
      for (int r = 0; r < 4; ++r) {
        int row = bm + wr + m * 16 + hi * 4 + r;
        int col = bn + wc + n * 16 + lo;
        if (OUT_BF16)
          ((short*)Cv)[(size_t)row * N + col] = f2bf(acc[m][n][r]);
        else
          ((float*)Cv)[(size_t)row * N + col] = acc[m][n][r];
      }
}

// ---------------- GEMM 256x256, 8 waves, BK=64 (2-phase structure) ----------------
template <int OUT_BF16>
__global__ __launch_bounds__(512) void k_gemm256(const short* __restrict__ A,
                                                 const short* __restrict__ Bt,
                                                 void* __restrict__ Cv, int M, int N, int K) {
  __shared__ short As[256 * 64];
  __shared__ short Bs[256 * 64];
  const int tid = threadIdx.x;
  const int bm = blockIdx.y * 256, bn = blockIdx.x * 256;
  const int w = tid >> 6, lane = tid & 63, lo = lane & 15, hi = lane >> 4;
  const int wr = (w >> 2) * 128, wc = (w & 3) * 64;
  f32x4 acc[8][4] = {};
  for (int k0 = 0; k0 < K; k0 += 64) {
#pragma unroll
    for (int rnd = 0; rnd < 4; ++rnd) {
      int i = rnd * 512 + tid;
      int row = i >> 3, c = i & 7;
      int src_col = (c ^ (row & 7)) * 8;
      gl16(&A[(size_t)(bm + row) * K + k0 + src_col], (char*)As + (size_t)i * 16);
      gl16(&Bt[(size_t)(bn + row) * K + k0 + src_col], (char*)Bs + (size_t)i * 16);
    }
    __syncthreads();
#pragma unroll
    for (int kk = 0; kk < 2; ++kk) {
      s16x8 af[8], bfr[4];
#pragma unroll
      for (int m = 0; m < 8; ++m) {
        int row = wr + m * 16 + lo;
        af[m] = *(const s16x8*)&As[row * 64 + (((kk * 4 + hi) ^ (row & 7)) * 8)];
      }
#pragma unroll
      for (int n = 0; n < 4; ++n) {
        int row = wc + n * 16 + lo;
        bfr[n] = *(const s16x8*)&Bs[row * 64 + (((kk * 4 + hi) ^ (row & 7)) * 8)];
      }
#pragma unroll
      for (int m = 0; m < 8; ++m)
#pragma unroll
        for (int n = 0; n < 4; ++n)
          acc[m][n] = __builtin_amdgcn_mfma_f32_16x16x32_bf16(af[m], bfr[n], acc[m][n], 0, 0, 0);
    }
    __syncthreads();
  }
#pragma unroll
  for (int m = 0; m < 8; ++m)
#pragma unroll
    for (int n = 0; n < 4; ++n)
#pragma unroll
      for (int r = 0; r < 4; ++r) {
        int row = bm + wr + m * 16 + hi * 4 + r;
        int col = bn + wc + n * 16 + lo;
        if (OUT_BF16)
          ((short*)Cv)[(size_t)row * N + col] = f2bf(acc[m][n][r]);
        else
          ((float*)Cv)[(size_t)row * N + col] = acc[m][n][r];
      }
}

// ---------------- per-(token,head) RMSNorm + RoPE, bf16 in/out ----------------
template <int NHEAD, int IN_ROW, int IN_HS>
__global__ __launch_bounds__(256) void k_norm_rope(const short* __restrict__ xin,
                                                   const float* __restrict__ wn,
                                                   const float* __restrict__ cosb,
                                                   const float* __restrict__ sinb,
                                                   short* __restrict__ xout) {
  int blk = blockIdx.x;
  int h = blk % NHEAD;
  int ts = blk / NHEAD;
  int d = threadIdx.x;
  float x = bf2f(xin[(size_t)ts * IN_ROW + h * IN_HS + d]);
  float ss = x * x;
#pragma unroll
  for (int m = 32; m >= 1; m >>= 1) ss += __shfl_xor(ss, m);
  __shared__ float sred[4];
  __shared__ float sn[256];
  int wid = d >> 6;
  if ((d & 63) == 0) sred[wid] = ss;
  __syncthreads();
  float tot = sred[0] + sred[1] + sred[2] + sred[3];
  float nv = x * rsqrtf(tot * (1.0f / 256.0f) + 1e-6f) * (1.0f + wn[d]);
  sn[d] = nv;
  __syncthreads();
  float o;
  if (d < 128) {
    float c = cosb[(size_t)ts * 128 + d];
    float s = sinb[(size_t)ts * 128 + d];
    o = (d < 64) ? (nv * c - sn[d + 64] * s) : (nv * c + sn[d - 64] * s);
  } else {
    o = nv;
  }
  xout[(size_t)blk * 256 + d] = f2bf(o);
}

// ---------------- GQA causal flash attention + sigmoid gate ----------------
// 256 blocks, 8 waves (512 thr, 2/SIMD), QBLK=128. Wave = (kv-half, q-group):
// qg = w&3 owns 32 q-rows (2 row-frags), kh = w>>2 owns 32 of each 64-kv tile.
// Each wave reads ONLY its kv-half of K/V from LDS (halved LDS traffic vs R7) while
// keeping 2 waves/SIMD TLP. Independent online softmax per kv-half; one-time LDS
// merge at the end. __launch_bounds__(512,1): VGPR cap 256 (R9's (512,2) capped at
// 128 -> 125MB scratch spill traffic, the entire regression).
#define ATTN_LDS 135168
__global__ __launch_bounds__(512, 1) void k_attn(const short* __restrict__ qb,
                                                 const short* __restrict__ kb,
                                                 const short* __restrict__ Vtg,
                                                 const short* __restrict__ qg,
                                                 short* __restrict__ og) {
  extern __shared__ char smem[];
  short* KbufS = (short*)smem;            // 2 bufs x [64 rows][32 chunks x 8]
  short* VbufS = (short*)(smem + 65536);  // 2 bufs x [256 rows][8 chunks x 8]
  float* Obuf = (float*)smem;             // post-loop: [128][260] f32 = 133120 B
  float* mlbuf = (float*)(smem + 133120); // post-loop: m/l exchange, 2048 B

  // XCD-aware decode: xcd = blockIdx % 8; (b,kvh) stream pinned to an XCD pair.
  const int raw = blockIdx.x;
  const int xcd = raw & 7, slot = raw >> 3;
  const int p = xcd >> 1, side = xcd & 1;
  const int id = side * 32 + slot;
  const int hgi = id & 3, qt = id >> 2;
  const int b = p >> 1, kvh = p & 1, h = kvh * 4 + hgi;
  const int q0 = qt * 128;
  const int tid = threadIdx.x;
  const int w = tid >> 6, lane = tid & 63, lo = lane & 15, hi = lane >> 4;
  const int qg_ = w & 3, kh = w >> 2;
  const int swz = lo & 7;

  const short* kbase = kb + ((size_t)(b * S_) * NKV_ + kvh) * HD_;
  const short* vbase = Vtg + (size_t)(b * 2 + kvh) * 256 * 2048;

  auto stage = [&](int kv0, int nb) {
#pragma unroll
    for (int rnd = 0; rnd < 4; ++rnd) {
      int i = rnd * 512 + tid;
      {
        int row = i >> 5, c = i & 31;
        const short* src = kbase + (size_t)(kv0 + row) * 512 + ((c ^ (row & 7)) * 8);
        gl16(src, smem + (size_t)nb * 32768 + (size_t)i * 16);
      }
      {
        int row = i >> 3, c = i & 7;
        const short* src = vbase + (size_t)row * 2048 + kv0 + ((c ^ (row & 7)) * 8);
        gl16(src, smem + 65536 + (size_t)nb * 32768 + (size_t)i * 16);
      }
    }
  };

  // Q fragments, two row-frags per wave: s -> rows q0 + qg_*32 + s*16 + lo
  s16x8 qf[2][8];
#pragma unroll
  for (int s = 0; s < 2; ++s) {
    size_t base = ((size_t)((b * S_ + q0 + qg_ * 32 + s * 16 + lo) * NH_) + h) * HD_;
#pragma unroll
    for (int t = 0; t < 8; ++t) qf[s][t] = *(const s16x8*)&qb[base + t * 32 + hi * 8];
  }
  f32x4 acc[2][16];
#pragma unroll
  for (int s = 0; s < 2; ++s)
#pragma unroll
    for (int t = 0; t < 16; ++t) acc[s][t] = (f32x4){0.f, 0.f, 0.f, 0.f};
  float m_run[2] = {-1e30f, -1e30f}, l_run[2] = {0.f, 0.f};
  const int qrow[2] = {q0 + qg_ * 32 + lo, q0 + qg_ * 32 + 16 + lo};

  stage(0, 0);
  __syncthreads();

  const int ntiles = 2 * qt + 2;
  int n = 0;
#pragma unroll 1
  for (int it = 0; it < ntiles; ++it) {
    const int kv0 = it * 64;
    if (it + 1 < ntiles) stage(kv0 + 64, n ^ 1);

    const short* Kb = KbufS + n * 16384;
    const short* Vb = VbufS + n * 16384;

    // S^T = K @ Q^T over this wave's 32-kv half (2 local nt)
    f32x4 sac[2][2];
#pragma unroll
    for (int s = 0; s < 2; ++s)
#pragma unroll
      for (int nt = 0; nt < 2; ++nt) sac[s][nt] = (f32x4){0.f, 0.f, 0.f, 0.f};
#pragma unroll
    for (int nt = 0; nt < 2; ++nt) {
      s16x8 kf[8];
#pragma unroll
      for (int t = 0; t < 8; ++t)
        kf[t] = *(const s16x8*)&Kb[(kh * 32 + nt * 16 + lo) * 256 + (((t * 4 + hi) ^ swz) * 8)];
#pragma unroll
      for (int t = 0; t < 8; ++t) {
        sac[0][nt] = __builtin_amdgcn_mfma_f32_16x16x32_bf16(kf[t], qf[0][t], sac[0][nt], 0, 0, 0);
        sac[1][nt] = __builtin_amdgcn_mfma_f32_16x16x32_bf16(kf[t], qf[1][t], sac[1][nt], 0, 0, 0);
      }
    }

    // in-register softmax per row-frag over 8 lane-local P values; pack to bf16
    int pk0[2][2], pk1[2][2];
#pragma unroll
    for (int s = 0; s < 2; ++s) {
      float pl[2][4];
      float mx = -1e30f;
#pragma unroll
      for (int nt = 0; nt < 2; ++nt)
#pragma unroll
        for (int r = 0; r < 4; ++r) {
          int kv = kv0 + kh * 32 + nt * 16 + hi * 4 + r;
          float v = sac[s][nt][r] * SCALE_;
          if (kv > qrow[s]) v = -1e30f;
          pl[nt][r] = v;
          mx = fmaxf(mx, v);
        }
      mx = fmaxf(mx, __shfl_xor(mx, 16));
      mx = fmaxf(mx, __shfl_xor(mx, 32));
      if (!__all(mx <= m_run[s] + 8.f)) {  // T13 defer-rescale
        float mnew = fmaxf(m_run[s], mx);
        float fs = __expf(m_run[s] - mnew);
        m_run[s] = mnew;
        l_run[s] *= fs;
        float f0 = __shfl(fs, 4 * hi + 0);
        float f1 = __shfl(fs, 4 * hi + 1);
        float f2 = __shfl(fs, 4 * hi + 2);
        float f3 = __shfl(fs, 4 * hi + 3);
#pragma unroll
        for (int t = 0; t < 16; ++t) {
          acc[s][t][0] *= f0;
          acc[s][t][1] *= f1;
          acc[s][t][2] *= f2;
          acc[s][t][3] *= f3;
        }
      }
      float rs = 0.f;
#pragma unroll
      for (int nt = 0; nt < 2; ++nt)
#pragma unroll
        for (int r = 0; r < 4; ++r) {
          pl[nt][r] = __expf(pl[nt][r] - m_run[s]);
          rs += pl[nt][r];
        }
      rs += __shfl_xor(rs, 16);
      rs += __shfl_xor(rs, 32);
      l_run[s] += rs;
#pragma unroll
      for (int nt = 0; nt < 2; ++nt) {
        asm("v_cvt_pk_bf16_f32 %0, %1, %2" : "=v"(pk0[s][nt]) : "v"(pl[nt][0]), "v"(pl[nt][1]));
        asm("v_cvt_pk_bf16_f32 %0, %1, %2" : "=v"(pk1[s][nt]) : "v"(pl[nt][2]), "v"(pl[nt][3]));
      }
    }

    // PV over this wave's 32-kv half: pa gathered per row-frag; vf shared (1:2)
    s16x8 pa[2];
#pragma unroll
    for (int s = 0; s < 2; ++s) {
      int pw[4];
#pragma unroll
      for (int dw = 0; dw < 4; ++dw) {
        int srcl = (2 * (hi & 1) + (dw >> 1)) * 16 + lo;
        int vA = __shfl((dw & 1) ? pk1[s][0] : pk0[s][0], srcl);
        int vB = __shfl((dw & 1) ? pk1[s][1] : pk0[s][1], srcl);
        pw[dw] = (hi & 2) ? vB : vA;
      }
      __builtin_memcpy(&pa[s], pw, 16);
    }
#pragma unroll
    for (int g = 0; g < 2; ++g) {
      s16x8 vf[8];
#pragma unroll
      for (int u = 0; u < 8; ++u) {
        int t = g * 8 + u;
        vf[u] = *(const s16x8*)&Vb[(t * 16 + lo) * 64 + (((kh * 4 + hi) ^ swz) * 8)];
      }
#pragma unroll
      for (int u = 0; u < 8; ++u) {
        int t = g * 8 + u;
        acc[0][t] = __builtin_amdgcn_mfma_f32_16x16x32_bf16(pa[0], vf[u], acc[0][t], 0, 0, 0);
        acc[1][t] = __builtin_amdgcn_mfma_f32_16x16x32_bf16(pa[1], vf[u], acc[1][t], 0, 0, 0);
      }
    }
    __syncthreads();
    n ^= 1;
  }

  // ---- merge the two kv-halves (per q-group) via LDS ----
  if (hi == 0) {
#pragma unroll
    for (int s = 0; s < 2; ++s) {
      mlbuf[((kh * 4 + qg_) * 2 + s) * 16 + lo] = m_run[s];
      mlbuf[256 + ((kh * 4 + qg_) * 2 + s) * 16 + lo] = l_run[s];
    }
  }
  __syncthreads();
  float fsr[2][4], lt[2];
#pragma unroll
  for (int s = 0; s < 2; ++s) {
    float mo = mlbuf[(((1 - kh) * 4 + qg_) * 2 + s) * 16 + lo];
    float lo_ = mlbuf[256 + (((1 - kh) * 4 + qg_) * 2 + s) * 16 + lo];
    float mm = fmaxf(m_run[s], mo);
    float fs_ = __expf(m_run[s] - mm);
    float fo_ = __expf(mo - mm);
    lt[s] = l_run[s] * fs_ + lo_ * fo_;
#pragma unroll
    for (int r = 0; r < 4; ++r) fsr[s][r] = __shfl(fs_, 4 * hi + r);
  }
  __syncthreads();  // mlbuf reads done before Obuf (alias region) writes
  if (kh == 1) {
#pragma unroll
    for (int s = 0; s < 2; ++s)
#pragma unroll
      for (int t = 0; t < 16; ++t)
#pragma unroll
        for (int r = 0; r < 4; ++r)
          Obuf[(qg_ * 32 + s * 16 + hi * 4 + r) * 260 + t * 16 + lo] = acc[s][t][r] * fsr[s][r];
  }
  __syncthreads();
  if (kh == 0) {
#pragma unroll
    for (int s = 0; s < 2; ++s) {
      float linv[4];
#pragma unroll
      for (int r = 0; r < 4; ++r) linv[r] = 1.0f / __shfl(lt[s], 4 * hi + r);
#pragma unroll
      for (int t = 0; t < 16; ++t)
#pragma unroll
        for (int r = 0; r < 4; ++r) {
          int row = q0 + qg_ * 32 + s * 16 + hi * 4 + r;
          int hd = t * 16 + lo;
          float o = (acc[s][t][r] * fsr[s][r] +
                     Obuf[(qg_ * 32 + s * 16 + hi * 4 + r) * 260 + t * 16 + lo]) *
                    linv[r];
          float g = bf2f(qg[(size_t)(b * S_ + row) * 4096 + h * 512 + 256 + hd]);
          float sg = 1.0f / (1.0f + __expf(-g));
          og[(size_t)(b * S_ + row) * 2048 + h * 256 + hd] = f2bf(o * sg);
        }
    }
  }
}

extern "C" void kernel_launch(void* const* d_in, const int* in_sizes, int n_in, void* d_out,
                              int out_size, void* d_ws, size_t ws_size, hipStream_t stream) {
  const float* hidden = (const float*)d_in[0];
  const float* cosb = (const float*)d_in[1];
  const float* sinb = (const float*)d_in[2];
  const float* Wq = (const float*)d_in[3];
  const float* Wk = (const float*)d_in[4];
  const float* Wv = (const float*)d_in[5];
  const float* Wo = (const float*)d_in[6];
  const float* qw = (const float*)d_in[7];
  const float* kw = (const float*)d_in[8];
  float* out = (float*)d_out;

  char* ws = (char*)d_ws;
  size_t off = 0;
  auto alloc = [&](size_t bytes) {
    void* p = ws + off;
    off += (bytes + 255) & ~(size_t)255;
    return p;
  };
  short* hb = (short*)alloc((size_t)TOK_ * HID_ * 2);
  short* WqT = (short*)alloc((size_t)4096 * 1024 * 2);
  short* kvT = (short*)alloc((size_t)1024 * 1024 * 2);
  short* WoT = (short*)alloc((size_t)1024 * 2048 * 2);
  short* qg = (short*)alloc((size_t)TOK_ * 4096 * 2);
  short* kvp = (short*)alloc((size_t)TOK_ * 1024 * 2);
  short* qb = (short*)alloc((size_t)TOK_ * 2048 * 2);
  short* kb = (short*)alloc((size_t)TOK_ * 512 * 2);
  short* og = (short*)alloc((size_t)TOK_ * 2048 * 2);
  short* Vtg = WqT;  // reuse: WqT dead after GEMM1
  (void)ws_size;
  (void)in_sizes;
  (void)n_in;
  (void)out_size;

  hipFuncSetAttribute((const void*)k_attn, hipFuncAttributeMaxDynamicSharedMemorySize,
                      ATTN_LDS);

  k_cast<<<(TOK_ * HID_ + 255) / 256, 256, 0, stream>>>(hidden, hb, TOK_ * HID_);
  k_wtrans<<<dim3(4096 / 32, 1024 / 32), 256, 0, stream>>>(Wq, WqT, 1024, 4096);
  k_wtrans<<<dim3(512 / 32, 1024 / 32), 256, 0, stream>>>(Wk, kvT, 1024, 512);
  k_wtrans<<<dim3(512 / 32, 1024 / 32), 256, 0, stream>>>(Wv, kvT + 512 * 1024, 1024, 512);
  k_wtrans<<<dim3(1024 / 32, 2048 / 32), 256, 0, stream>>>(Wo, WoT, 2048, 1024);

  k_gemm256<1><<<dim3(16, 16), 512, 0, stream>>>(hb, WqT, qg, 4096, 4096, 1024);
  k_gemm_bt<1><<<dim3(8, 32), 256, 0, stream>>>(hb, kvT, kvp, 4096, 1024, 1024);

  k_norm_rope<NH_, 4096, 512><<<TOK_ * NH_, 256, 0, stream>>>(qg, qw, cosb, sinb, qb);
  k_norm_rope<NKV_, 1024, 256><<<TOK_ * NKV_, 256, 0, stream>>>(kvp, kw, cosb, sinb, kb);
  k_vtrans<<<dim3(64, 8, 4), 256, 0, stream>>>(kvp, Vtg);

  k_attn<<<256, 512, ATTN_LDS, stream>>>(qb, kb, Vtg, qg, og);

  k_gemm_bt<0><<<dim3(8, 32), 256, 0, stream>>>(og, WoT, out, 4096, 1024, 2048);
}

// Round 11
// 232.874 us; speedup vs baseline: 1.7537x; 1.7508x over previous
//
#include <hip/hip_runtime.h>
#include <cstdint>
#include <cstddef>

#define B_ 2
#define S_ 2048
#define HID_ 1024
#define NH_ 8
#define NKV_ 2
#define HD_ 256
#define ROT_ 128
#define TOK_ (B_ * S_)
#define SCALE_ 0.0625f

typedef __attribute__((ext_vector_type(8))) short s16x8;
typedef __attribute__((ext_vector_type(4))) float f32x4;

__device__ __forceinline__ float bf2f(short u) {
  unsigned t = ((unsigned)(unsigned short)u) << 16;
  float f;
  __builtin_memcpy(&f, &t, 4);
  return f;
}
__device__ __forceinline__ short f2bf(float f) {
  unsigned u;
  __builtin_memcpy(&u, &f, 4);
  u += 0x7fffu + ((u >> 16) & 1);
  return (short)(u >> 16);
}

// async global->LDS 16B (gfx950). LDS dest is wave-uniform base + lane*16.
__device__ __forceinline__ void gl16(const void* g, void* l) {
  __builtin_amdgcn_global_load_lds((const __attribute__((address_space(1))) int*)g,
                                   (__attribute__((address_space(3))) int*)l, 16, 0, 0);
}

// ---------------- elementwise cast fp32 -> bf16 ----------------
__global__ __launch_bounds__(256) void k_cast(const float* __restrict__ in,
                                              short* __restrict__ out, int n) {
  int i = blockIdx.x * 256 + threadIdx.x;
  if (i < n) out[i] = f2bf(in[i]);
}

// ---------------- tiled transpose + cast: in[R][C] fp32 -> out[C][R] bf16 ----------------
__global__ __launch_bounds__(256) void k_wtrans(const float* __restrict__ in,
                                                short* __restrict__ out, int R, int C) {
  __shared__ short tile[32][33];
  int tx = threadIdx.x & 31, ty = threadIdx.x >> 5;
  int r0 = blockIdx.y * 32, c0 = blockIdx.x * 32;
#pragma unroll
  for (int p = 0; p < 4; ++p)
    tile[ty + p * 8][tx] = f2bf(in[(size_t)(r0 + ty + p * 8) * C + c0 + tx]);
  __syncthreads();
#pragma unroll
  for (int p = 0; p < 4; ++p)
    out[(size_t)(c0 + ty + p * 8) * R + r0 + tx] = tile[tx][ty + p * 8];
}

// ---------------- V transpose: kvp v-part -> Vtg[b*2+kvh][256][2048] bf16 ----------------
__global__ __launch_bounds__(256) void k_vtrans(const short* __restrict__ kvp,
                                                short* __restrict__ Vtg) {
  __shared__ short tile[32][33];
  int bh = blockIdx.z;
  int b = bh >> 1, kvh = bh & 1;
  int s0 = blockIdx.x * 32, d0 = blockIdx.y * 32;
  int tx = threadIdx.x & 31, ty = threadIdx.x >> 5;
#pragma unroll
  for (int p = 0; p < 4; ++p) {
    int sr = ty + p * 8;
    tile[sr][tx] = kvp[(size_t)(b * S_ + s0 + sr) * 1024 + 512 + kvh * 256 + d0 + tx];
  }
  __syncthreads();
#pragma unroll
  for (int p = 0; p < 4; ++p) {
    int dr = ty + p * 8;
    Vtg[((size_t)bh * 256 + d0 + dr) * 2048 + s0 + tx] = tile[tx][dr];
  }
}

// ---------------- GEMM 128x128, BK=64, 2-phase double-buffered gl16 pipeline --------
// T3 minimum-2-phase: issue next tile's global_load_lds BEFORE current compute; one
// barrier per K-tile drains it after compute has covered the HBM latency.
// LDS 2 x (A 16KB + B 16KB) = 64KB dynamic -> 2 blocks/CU (launch_bounds(256,2)).
template <int OUT_BF16>
__global__ __launch_bounds__(256, 2) void k_gemm_bt(const short* __restrict__ A,
                                                    const short* __restrict__ Bt,
                                                    void* __restrict__ Cv, int M, int N,
                                                    int K) {
  extern __shared__ char smem[];
  const int tid = threadIdx.x;
  const int bm = blockIdx.y * 128, bn = blockIdx.x * 128;
  const int w = tid >> 6, lane = tid & 63, lo = lane & 15, hi = lane >> 4;
  const int wr = (w >> 1) * 64, wc = (w & 1) * 64;
  f32x4 acc[4][4] = {};

  auto stage = [&](int k0, int nb) {
#pragma unroll
    for (int rnd = 0; rnd < 4; ++rnd) {
      int i = rnd * 256 + tid;  // slot 0..1023
      int row = i >> 3, c = i & 7;
      int src_col = (c ^ (row & 7)) * 8;
      gl16(&A[(size_t)(bm + row) * K + k0 + src_col], smem + (size_t)nb * 16384 + (size_t)i * 16);
      gl16(&Bt[(size_t)(bn + row) * K + k0 + src_col],
           smem + 32768 + (size_t)nb * 16384 + (size_t)i * 16);
    }
  };

  stage(0, 0);
  __syncthreads();
  int nb = 0;
  for (int k0 = 0; k0 < K; k0 += 64) {
    if (k0 + 64 < K) stage(k0 + 64, nb ^ 1);  // loads fly under compute below
    const short* As = (const short*)(smem + (size_t)nb * 16384);
    const short* Bs = (const short*)(smem + 32768 + (size_t)nb * 16384);
    s16x8 af[2][4], bfr[2][4];
#pragma unroll
    for (int kk = 0; kk < 2; ++kk) {
#pragma unroll
      for (int m = 0; m < 4; ++m) {
        int row = wr + m * 16 + lo;
        af[kk][m] = *(const s16x8*)&As[row * 64 + (((kk * 4 + hi) ^ (row & 7)) * 8)];
      }
#pragma unroll
      for (int n = 0; n < 4; ++n) {
        int row = wc + n * 16 + lo;
        bfr[kk][n] = *(const s16x8*)&Bs[row * 64 + (((kk * 4 + hi) ^ (row & 7)) * 8)];
      }
    }
#pragma unroll
    for (int kk = 0; kk < 2; ++kk)
#pragma unroll
      for (int m = 0; m < 4; ++m)
#pragma unroll
        for (int n = 0; n < 4; ++n)
          acc[m][n] =
              __builtin_amdgcn_mfma_f32_16x16x32_bf16(af[kk][m], bfr[kk][n], acc[m][n], 0, 0, 0);
    __syncthreads();  // drains vmcnt (next tile) + ensures reads done before overwrite
    nb ^= 1;
  }
#pragma unroll
  for (int m = 0; m < 4; ++m)
#pragma unroll
    for (int n = 0; n < 4; ++n)
#pragma unroll
      for (int r = 0; r < 4; ++r) {
        int row = bm + wr + m * 16 + hi * 4 + r;
        int col = bn + wc + n * 16 + lo;
        if (OUT_BF16)
          ((short*)Cv)[(size_t)row * N + col] = f2bf(acc[m][n][r]);
        else
          ((float*)Cv)[(size_t)row * N + col] = acc[m][n][r];
      }
}

// ---------------- GEMM 256x256, 8 waves, BK=64, 2-phase double-buffered -------------
// LDS 2 x (A 32KB + B 32KB) = 128KB dynamic -> 1 block/CU (8 waves = 2/SIMD).
template <int OUT_BF16>
__global__ __launch_bounds__(512, 1) void k_gemm256(const short* __restrict__ A,
                                                    const short* __restrict__ Bt,
                                                    void* __restrict__ Cv, int M, int N,
                                                    int K) {
  extern __shared__ char smem[];
  const int tid = threadIdx.x;
  const int bm = blockIdx.y * 256, bn = blockIdx.x * 256;
  const int w = tid >> 6, lane = tid & 63, lo = lane & 15, hi = lane >> 4;
  const int wr = (w >> 2) * 128, wc = (w & 3) * 64;
  f32x4 acc[8][4] = {};

  auto stage = [&](int k0, int nb) {
#pragma unroll
    for (int rnd = 0; rnd < 4; ++rnd) {
      int i = rnd * 512 + tid;  // slot 0..2047
      int row = i >> 3, c = i & 7;
      int src_col = (c ^ (row & 7)) * 8;
      gl16(&A[(size_t)(bm + row) * K + k0 + src_col], smem + (size_t)nb * 32768 + (size_t)i * 16);
      gl16(&Bt[(size_t)(bn + row) * K + k0 + src_col],
           smem + 65536 + (size_t)nb * 32768 + (size_t)i * 16);
    }
  };

  stage(0, 0);
  __syncthreads();
  int nb = 0;
  for (int k0 = 0; k0 < K; k0 += 64) {
    if (k0 + 64 < K) stage(k0 + 64, nb ^ 1);
    const short* As = (const short*)(smem + (size_t)nb * 32768);
    const short* Bs = (const short*)(smem + 65536 + (size_t)nb * 32768);
#pragma unroll
    for (int kk = 0; kk < 2; ++kk) {
      s16x8 bfr[4];
#pragma unroll
      for (int n = 0; n < 4; ++n) {
        int row = wc + n * 16 + lo;
        bfr[n] = *(const s16x8*)&Bs[row * 64 + (((kk * 4 + hi) ^ (row & 7)) * 8)];
      }
      // process m in two groups of 4 to limit arch-VGPR peak (8-wave cap = 128 arch)
#pragma unroll
      for (int g = 0; g < 2; ++g) {
        s16x8 af[4];
#pragma unroll
        for (int u = 0; u < 4; ++u) {
          int row = wr + (g * 4 + u) * 16 + lo;
          af[u] = *(const s16x8*)&As[row * 64 + (((kk * 4 + hi) ^ (row & 7)) * 8)];
        }
#pragma unroll
        for (int u = 0; u < 4; ++u)
#pragma unroll
          for (int n = 0; n < 4; ++n)
            acc[g * 4 + u][n] =
                __builtin_amdgcn_mfma_f32_16x16x32_bf16(af[u], bfr[n], acc[g * 4 + u][n], 0, 0, 0);
      }
    }
    __syncthreads();
    nb ^= 1;
  }
#pragma unroll
  for (int m = 0; m < 8; ++m)
#pragma unroll
    for (int n = 0; n < 4; ++n)
#pragma unroll
      for (int r = 0; r < 4; ++r) {
        int row = bm + wr + m * 16 + hi * 4 + r;
        int col = bn + wc + n * 16 + lo;
        if (OUT_BF16)
          ((short*)Cv)[(size_t)row * N + col] = f2bf(acc[m][n][r]);
        else
          ((float*)Cv)[(size_t)row * N + col] = acc[m][n][r];
      }
}

// ---------------- per-(token,head) RMSNorm + RoPE, bf16 in/out ----------------
template <int NHEAD, int IN_ROW, int IN_HS>
__global__ __launch_bounds__(256) void k_norm_rope(const short* __restrict__ xin,
                                                   const float* __restrict__ wn,
                                                   const float* __restrict__ cosb,
                                                   const float* __restrict__ sinb,
                                                   short* __restrict__ xout) {
  int blk = blockIdx.x;
  int h = blk % NHEAD;
  int ts = blk / NHEAD;
  int d = threadIdx.x;
  float x = bf2f(xin[(size_t)ts * IN_ROW + h * IN_HS + d]);
  float ss = x * x;
#pragma unroll
  for (int m = 32; m >= 1; m >>= 1) ss += __shfl_xor(ss, m);
  __shared__ float sred[4];
  __shared__ float sn[256];
  int wid = d >> 6;
  if ((d & 63) == 0) sred[wid] = ss;
  __syncthreads();
  float tot = sred[0] + sred[1] + sred[2] + sred[3];
  float nv = x * rsqrtf(tot * (1.0f / 256.0f) + 1e-6f) * (1.0f + wn[d]);
  sn[d] = nv;
  __syncthreads();
  float o;
  if (d < 128) {
    float c = cosb[(size_t)ts * 128 + d];
    float s = sinb[(size_t)ts * 128 + d];
    o = (d < 64) ? (nv * c - sn[d + 64] * s) : (nv * c + sn[d - 64] * s);
  } else {
    o = nv;
  }
  xout[(size_t)blk * 256 + d] = f2bf(o);
}

// ---------------- GQA causal flash attention + sigmoid gate (R7, measured 105us) ----
// 256 blocks, 8 waves, QBLK=128 (16 rows/wave), KVBLK=64 double-buffered, gl16+swizzle.
// SWAPPED QK^T: mfma(K,Q) -> S^T, q-row lane-local => in-register softmax; T13
// defer-rescale; cvt_pk + shfl gather for PV A-frags. VGPR ~120 -> no spill at 2/SIMD.
#define ATTN_LDS 131072
__global__ __launch_bounds__(512, 1) void k_attn(const short* __restrict__ qb,
                                                 const short* __restrict__ kb,
                                                 const short* __restrict__ Vtg,
                                                 const short* __restrict__ qg,
                                                 short* __restrict__ og) {
  extern __shared__ char smem[];
  short* KbufS = (short*)smem;            // 2 bufs x [64 rows][32 chunks x 8]
  short* VbufS = (short*)(smem + 65536);  // 2 bufs x [256 rows][8 chunks x 8]

  // XCD-aware decode: xcd = blockIdx % 8; (b,kvh) stream pinned to an XCD pair.
  const int raw = blockIdx.x;
  const int xcd = raw & 7, slot = raw >> 3;
  const int p = xcd >> 1, side = xcd & 1;
  const int id = side * 32 + slot;
  const int hgi = id & 3, qt = id >> 2;
  const int b = p >> 1, kvh = p & 1, h = kvh * 4 + hgi;
  const int q0 = qt * 128;
  const int tid = threadIdx.x;
  const int w = tid >> 6, lane = tid & 63, lo = lane & 15, hi = lane >> 4;
  const int swz = lo & 7;

  const short* kbase = kb + ((size_t)(b * S_) * NKV_ + kvh) * HD_;
  const short* vbase = Vtg + (size_t)(b * 2 + kvh) * 256 * 2048;

  auto stage = [&](int kv0, int nb) {
#pragma unroll
    for (int rnd = 0; rnd < 4; ++rnd) {
      int i = rnd * 512 + tid;
      {
        int row = i >> 5, c = i & 31;
        const short* src = kbase + (size_t)(kv0 + row) * 512 + ((c ^ (row & 7)) * 8);
        gl16(src, smem + (size_t)nb * 32768 + (size_t)i * 16);
      }
      {
        int row = i >> 3, c = i & 7;
        const short* src = vbase + (size_t)row * 2048 + kv0 + ((c ^ (row & 7)) * 8);
        gl16(src, smem + 65536 + (size_t)nb * 32768 + (size_t)i * 16);
      }
    }
  };

  // Q fragments (B-operand): n=lane&15 -> q-row, k=(lane>>4)*8+j
  s16x8 qf[8];
  {
    size_t base = ((size_t)((b * S_ + q0 + w * 16 + lo) * NH_) + h) * HD_;
#pragma unroll
    for (int t = 0; t < 8; ++t) qf[t] = *(const s16x8*)&qb[base + t * 32 + hi * 8];
  }
  f32x4 acc[16];
#pragma unroll
  for (int t = 0; t < 16; ++t) acc[t] = (f32x4){0.f, 0.f, 0.f, 0.f};
  float m_run = -1e30f, l_run = 0.f;
  const int qrow = q0 + w * 16 + lo;

  stage(0, 0);
  __syncthreads();

  const int ntiles = 2 * qt + 2;
  int n = 0;
#pragma unroll 1
  for (int it = 0; it < ntiles; ++it) {
    const int kv0 = it * 64;
    if (it + 1 < ntiles) stage(kv0 + 64, n ^ 1);

    const short* Kb = KbufS + n * 16384;
    const short* Vb = VbufS + n * 16384;

    // S^T = K @ Q^T over HD=256 (swapped operands)
    f32x4 sacc[4] = {};
#pragma unroll
    for (int nt = 0; nt < 4; ++nt) {
      s16x8 kf[8];
#pragma unroll
      for (int t = 0; t < 8; ++t)
        kf[t] = *(const s16x8*)&Kb[(nt * 16 + lo) * 256 + (((t * 4 + hi) ^ swz) * 8)];
#pragma unroll
      for (int t = 0; t < 8; ++t)
        sacc[nt] = __builtin_amdgcn_mfma_f32_16x16x32_bf16(kf[t], qf[t], sacc[nt], 0, 0, 0);
    }

    // in-register softmax
    float pv[4][4];
    float mx = -1e30f;
#pragma unroll
    for (int nt = 0; nt < 4; ++nt)
#pragma unroll
      for (int r = 0; r < 4; ++r) {
        int kv = kv0 + nt * 16 + hi * 4 + r;
        float s = sacc[nt][r] * SCALE_;
        if (kv > qrow) s = -1e30f;
        pv[nt][r] = s;
        mx = fmaxf(mx, s);
      }
    mx = fmaxf(mx, __shfl_xor(mx, 16));
    mx = fmaxf(mx, __shfl_xor(mx, 32));
    if (!__all(mx <= m_run + 8.f)) {  // T13 defer-rescale
      float mnew = fmaxf(m_run, mx);
      float fs = __expf(m_run - mnew);
      m_run = mnew;
      l_run *= fs;
      float f0 = __shfl(fs, 4 * hi + 0);
      float f1 = __shfl(fs, 4 * hi + 1);
      float f2 = __shfl(fs, 4 * hi + 2);
      float f3 = __shfl(fs, 4 * hi + 3);
#pragma unroll
      for (int t = 0; t < 16; ++t) {
        acc[t][0] *= f0;
        acc[t][1] *= f1;
        acc[t][2] *= f2;
        acc[t][3] *= f3;
      }
    }
    float rs = 0.f;
#pragma unroll
    for (int nt = 0; nt < 4; ++nt)
#pragma unroll
      for (int r = 0; r < 4; ++r) {
        pv[nt][r] = __expf(pv[nt][r] - m_run);
        rs += pv[nt][r];
      }
    rs += __shfl_xor(rs, 16);
    rs += __shfl_xor(rs, 32);
    l_run += rs;

    // pack P to bf16 pairs
    int pk0[4], pk1[4];
#pragma unroll
    for (int nt = 0; nt < 4; ++nt) {
      asm("v_cvt_pk_bf16_f32 %0, %1, %2" : "=v"(pk0[nt]) : "v"(pv[nt][0]), "v"(pv[nt][1]));
      asm("v_cvt_pk_bf16_f32 %0, %1, %2" : "=v"(pk1[nt]) : "v"(pv[nt][2]), "v"(pv[nt][3]));
    }

    // PV: A-frag P[m=q=lo][k=kv] gathered via shfl from S^T owners
#pragma unroll
    for (int ks = 0; ks < 2; ++ks) {
      int pw[4];
#pragma unroll
      for (int dw = 0; dw < 4; ++dw) {
        int srcl = (2 * (hi & 1) + (dw >> 1)) * 16 + lo;
        int vA = __shfl((dw & 1) ? pk1[2 * ks] : pk0[2 * ks], srcl);
        int vB = __shfl((dw & 1) ? pk1[2 * ks + 1] : pk0[2 * ks + 1], srcl);
        pw[dw] = (hi & 2) ? vB : vA;
      }
      s16x8 pa;
      __builtin_memcpy(&pa, pw, 16);
#pragma unroll
      for (int g = 0; g < 2; ++g) {
        s16x8 vf[8];
#pragma unroll
        for (int u = 0; u < 8; ++u) {
          int t = g * 8 + u;
          vf[u] = *(const s16x8*)&Vb[(t * 16 + lo) * 64 + (((ks * 4 + hi) ^ swz) * 8)];
        }
#pragma unroll
        for (int u = 0; u < 8; ++u) {
          int t = g * 8 + u;
          acc[t] = __builtin_amdgcn_mfma_f32_16x16x32_bf16(pa, vf[u], acc[t], 0, 0, 0);
        }
      }
    }
    __syncthreads();
    n ^= 1;
  }

  // epilogue: normalize, sigmoid gate, store bf16
  float linv[4];
#pragma unroll
  for (int r = 0; r < 4; ++r) linv[r] = 1.0f / __shfl(l_run, 4 * hi + r);
#pragma unroll
  for (int t = 0; t < 16; ++t)
#pragma unroll
    for (int r = 0; r < 4; ++r) {
      int row = q0 + w * 16 + hi * 4 + r;
      int hd = t * 16 + lo;
      float o = acc[t][r] * linv[r];
      float g = bf2f(qg[(size_t)(b * S_ + row) * 4096 + h * 512 + 256 + hd]);
      float sg = 1.0f / (1.0f + __expf(-g));
      og[(size_t)(b * S_ + row) * 2048 + h * 256 + hd] = f2bf(o * sg);
    }
}

extern "C" void kernel_launch(void* const* d_in, const int* in_sizes, int n_in, void* d_out,
                              int out_size, void* d_ws, size_t ws_size, hipStream_t stream) {
  const float* hidden = (const float*)d_in[0];
  const float* cosb = (const float*)d_in[1];
  const float* sinb = (const float*)d_in[2];
  const float* Wq = (const float*)d_in[3];
  const float* Wk = (const float*)d_in[4];
  const float* Wv = (const float*)d_in[5];
  const float* Wo = (const float*)d_in[6];
  const float* qw = (const float*)d_in[7];
  const float* kw = (const float*)d_in[8];
  float* out = (float*)d_out;

  char* ws = (char*)d_ws;
  size_t off = 0;
  auto alloc = [&](size_t bytes) {
    void* p = ws + off;
    off += (bytes + 255) & ~(size_t)255;
    return p;
  };
  short* hb = (short*)alloc((size_t)TOK_ * HID_ * 2);
  short* WqT = (short*)alloc((size_t)4096 * 1024 * 2);
  short* kvT = (short*)alloc((size_t)1024 * 1024 * 2);
  short* WoT = (short*)alloc((size_t)1024 * 2048 * 2);
  short* qg = (short*)alloc((size_t)TOK_ * 4096 * 2);
  short* kvp = (short*)alloc((size_t)TOK_ * 1024 * 2);
  short* qb = (short*)alloc((size_t)TOK_ * 2048 * 2);
  short* kb = (short*)alloc((size_t)TOK_ * 512 * 2);
  short* og = (short*)alloc((size_t)TOK_ * 2048 * 2);
  short* Vtg = WqT;  // reuse: WqT dead after GEMM1
  (void)ws_size;
  (void)in_sizes;
  (void)n_in;
  (void)out_size;

  hipFuncSetAttribute((const void*)k_attn, hipFuncAttributeMaxDynamicSharedMemorySize,
                      ATTN_LDS);
  hipFuncSetAttribute((const void*)k_gemm256<1>, hipFuncAttributeMaxDynamicSharedMemorySize,
                      131072);
  hipFuncSetAttribute((const void*)k_gemm_bt<1>, hipFuncAttributeMaxDynamicSharedMemorySize,
                      65536);
  hipFuncSetAttribute((const void*)k_gemm_bt<0>, hipFuncAttributeMaxDynamicSharedMemorySize,
                      65536);

  k_cast<<<(TOK_ * HID_ + 255) / 256, 256, 0, stream>>>(hidden, hb, TOK_ * HID_);
  k_wtrans<<<dim3(4096 / 32, 1024 / 32), 256, 0, stream>>>(Wq, WqT, 1024, 4096);
  k_wtrans<<<dim3(512 / 32, 1024 / 32), 256, 0, stream>>>(Wk, kvT, 1024, 512);
  k_wtrans<<<dim3(512 / 32, 1024 / 32), 256, 0, stream>>>(Wv, kvT + 512 * 1024, 1024, 512);
  k_wtrans<<<dim3(1024 / 32, 2048 / 32), 256, 0, stream>>>(Wo, WoT, 2048, 1024);

  k_gemm256<1><<<dim3(16, 16), 512, 131072, stream>>>(hb, WqT, qg, 4096, 4096, 1024);
  k_gemm_bt<1><<<dim3(8, 32), 256, 65536, stream>>>(hb, kvT, kvp, 4096, 1024, 1024);

  k_norm_rope<NH_, 4096, 512><<<TOK_ * NH_, 256, 0, stream>>>(qg, qw, cosb, sinb, qb);
  k_norm_rope<NKV_, 1024, 256><<<TOK_ * NKV_, 256, 0, stream>>>(kvp, kw, cosb, sinb, kb);
  k_vtrans<<<dim3(64, 8, 4), 256, 0, stream>>>(kvp, Vtg);

  k_attn<<<256, 512, ATTN_LDS, stream>>>(qb, kb, Vtg, qg, og);

  k_gemm_bt<0><<<dim3(8, 32), 256, 65536, stream>>>(og, WoT, out, 4096, 1024, 2048);
}